// Round 4
// baseline (834.507 us; speedup 1.0000x reference)
//
#include <hip/hip_runtime.h>
#include <hip/hip_cooperative_groups.h>

namespace cg = cooperative_groups;

#define NN 100000
#define NE 1600000
#define NP 200000
#define CH 128
#define LK 264    // padded LDS row stride (fp16 elems)

#define BSH 6                    // 64 nodes per bucket
#define NB  1563                 // ceil(NN / 64)
#define CAP3 4096                // finalize LDS edge capacity (mean bucket = 1024)
#define CSB 25                   // colscan blocks: ceil(NB/64)
#define SMEM_BYTES 33792         // 64*264*2 — max over all phases
#define MAXGB 1024

typedef _Float16 f16x8 __attribute__((ext_vector_type(8)));
typedef float f32x4 __attribute__((ext_vector_type(4)));

struct Params {
    const float* x; const int* src; const int* dst; const float* ew;
    const int* ps; const int* pd;
    const float* w1r; const float* b1; const float* w1o;
    const float* w2r; const float* b2; const float* w2o;
    _Float16* xh; _Float16* hh; _Float16* zh;
    int* hist; int* totals; int* base; int* row_ptr; int* syncc;
    int2* tmp; int2* csr;
    _Float16* w1t; _Float16* w2t;
    float* out;
};

// per-block edge range for GB blocks
__device__ __forceinline__ void edge_range(int bid, int GB, int& st, int& cnt) {
    int epb = NE / GB, rem = NE % GB;
    st = bid * epb + min(bid, rem);
    cnt = epb + (bid < rem ? 1 : 0);
}

// ---- P1a: cast x -> fp16 (grid-stride) ----
__device__ __forceinline__ void d_cast(const float* __restrict__ x, _Float16* __restrict__ xh,
                                       int gid, int gstride) {
    for (int i = gid; i < NN * CH / 8; i += gstride) {
        const float4* p = (const float4*)x + (size_t)i * 2;
        float4 a = p[0], b = p[1];
        f16x8 o = { (_Float16)a.x, (_Float16)a.y, (_Float16)a.z, (_Float16)a.w,
                    (_Float16)b.x, (_Float16)b.y, (_Float16)b.z, (_Float16)b.w };
        *((f16x8*)xh + i) = o;
    }
}

// ---- P1b: weight transpose (wt[n][k] layout, [rel|root] stacked on k) ----
__device__ __forceinline__ void d_weights(const float* __restrict__ w1r, const float* __restrict__ w1o,
                                          const float* __restrict__ w2r, const float* __restrict__ w2o,
                                          _Float16* __restrict__ w1t, _Float16* __restrict__ w2t,
                                          int gid) {
    if (gid < 65536) {
        int which = gid >> 15;
        int li = gid & 32767;
        int n = li >> 8, k = li & 255;
        const float* wr = which ? w2r : w1r;
        const float* wo = which ? w2o : w1o;
        _Float16* wt = which ? w2t : w1t;
        float v = (k < 128) ? wr[k * 128 + n] : wo[(k - 128) * 128 + n];
        wt[li] = (_Float16)v;
    }
}

// ---- P1c: per-block bucket histogram over this block's edge range ----
__device__ __forceinline__ void d_hist(const int* __restrict__ dst, int* __restrict__ hist,
                                       int bid, int GB, int tid, void* smem) {
    int* s_h = (int*)smem;
    for (int i = tid; i < NB; i += 512) s_h[i] = 0;
    __syncthreads();
    int st, cnt; edge_range(bid, GB, st, cnt);
    for (int e = st + tid; e < st + cnt; e += 512)
        atomicAdd(&s_h[dst[e] >> BSH], 1);
    __syncthreads();
    int* row = hist + (size_t)bid * NB;
    for (int i = tid; i < NB; i += 512) row[i] = s_h[i];
    __syncthreads();
}

// ---- P2: column exclusive scan over GB hist rows (block per 64 buckets) + fused base scan ----
__device__ __forceinline__ void d_colscan(int* __restrict__ hist, int* __restrict__ totals,
                                          int* __restrict__ base, int* __restrict__ syncc,
                                          int bid, int GB, int tid, void* smem) {
    if (bid >= CSB) return;
    int* qs = (int*)smem;            // [8][64]
    int* ws = qs + 512;              // [8]
    int* s_sync = ws + 8;
    const int c = tid >> 6, lb = tid & 63;
    const int b = bid * 64 + lb;
    const bool valid = (b < NB);
    const int rows = GB >> 3;        // rows per chunk (GB % 8 == 0)

    int s = 0;
    if (valid)
        for (int g = c * rows; g < (c + 1) * rows; ++g)
            s += hist[(size_t)g * NB + b];
    qs[c * 64 + lb] = s;
    __syncthreads();

    if (tid < 64) {
        int a[8], tot = 0;
#pragma unroll
        for (int j = 0; j < 8; j++) a[j] = qs[j * 64 + tid];
        int run = 0;
#pragma unroll
        for (int j = 0; j < 8; j++) { qs[j * 64 + tid] = run; run += a[j]; }
        tot = run;
        int bt = bid * 64 + tid;
        if (bt < NB) totals[bt] = tot;
    }
    __syncthreads();

    int run = qs[c * 64 + lb];
    if (valid) {
        for (int g = c * rows; g < (c + 1) * rows; ++g) {
            size_t idx = (size_t)g * NB + b;
            int v = hist[idx];
            hist[idx] = run;
            run += v;
        }
    }

    // last-block: exclusive scan totals -> base
    __syncthreads();
    if (tid == 0) {
        __threadfence();
        *s_sync = atomicAdd(syncc, 1);
    }
    __syncthreads();
    if (*s_sync != CSB - 1) return;
    __threadfence();

    const int c0 = tid * 4;          // 512*4 = 2048 >= NB
    int incl4[4];
    int cs = 0;
#pragma unroll
    for (int k = 0; k < 4; k++) {
        int i = c0 + k;
        int t = (i < NB) ? totals[i] : 0;
        cs += t;
        incl4[k] = cs;
    }
    int lane = tid & 63, w = tid >> 6;
    int incl = cs;
#pragma unroll
    for (int off = 1; off < 64; off <<= 1) {
        int n = __shfl_up(incl, off, 64);
        if (lane >= off) incl += n;
    }
    if (lane == 63) ws[w] = incl;
    __syncthreads();
    int woff = 0;
    for (int j = 0; j < w; j++) woff += ws[j];
    int chunk_excl = woff + incl - cs;
    if (tid == 0) base[0] = 0;
#pragma unroll
    for (int k = 0; k < 4; k++) {
        int i = c0 + k;
        if (i < NB) base[i + 1] = chunk_excl + incl4[k];
    }
}

// ---- P3: scatter edges into bucket regions; x = src | dst_local<<17, y = fp32 weight ----
__device__ __forceinline__ void d_scatter(const int* __restrict__ src, const int* __restrict__ dst,
                                          const float* __restrict__ ew, const int* __restrict__ hist,
                                          const int* __restrict__ base, int2* __restrict__ tmp,
                                          int bid, int GB, int tid, void* smem) {
    int* s_cur = (int*)smem;
    const int* row = hist + (size_t)bid * NB;
    for (int i = tid; i < NB; i += 512) s_cur[i] = base[i] + row[i];
    __syncthreads();
    int st, cnt; edge_range(bid, GB, st, cnt);
    for (int e = st + tid; e < st + cnt; e += 512) {
        int d = dst[e];
        int b = d >> BSH;
        int pos = atomicAdd(&s_cur[b], 1);
        tmp[pos] = make_int2(src[e] | ((d & 63) << 17), __float_as_int(ew[e]));
    }
    __syncthreads();
}

// ---- P4: finalize one bucket -> node-grouped csr + row_ptr ----
__device__ __forceinline__ void d_finalize(const int2* __restrict__ tmp, const int* __restrict__ base,
                                           int* __restrict__ row_ptr, int2* __restrict__ csr,
                                           int b, int tid, void* smem) {
    int2* s_e = (int2*)smem;                       // CAP3 entries = 32768 B
    int* s_cnt = (int*)((char*)smem + 32768);      // 64
    int* s_off = s_cnt + 64;                       // 64
    int lo = base[b], hi = base[b + 1];
    int size = hi - lo;
    int nbase = b << BSH;
    int ncnt = min(64, NN - nbase);
    if (tid < 64) s_cnt[tid] = 0;
    bool inlds = (size <= CAP3);
    __syncthreads();
    if (inlds) {
        for (int i = tid; i < size; i += 512) {
            int2 e = tmp[lo + i];
            s_e[i] = e;
            atomicAdd(&s_cnt[(e.x >> 17) & 63], 1);
        }
    } else {
        for (int i = tid; i < size; i += 512) {
            int2 e = tmp[lo + i];
            atomicAdd(&s_cnt[(e.x >> 17) & 63], 1);
        }
    }
    __syncthreads();
    if (tid < 64) {   // wave 0: shuffle exclusive scan
        int v = s_cnt[tid];
        int incl = v;
#pragma unroll
        for (int off = 1; off < 64; off <<= 1) {
            int n = __shfl_up(incl, off, 64);
            if (tid >= off) incl += n;
        }
        int excl = incl - v;
        s_off[tid] = excl;
        s_cnt[tid] = excl;
    }
    __syncthreads();
    if (tid < ncnt) row_ptr[nbase + tid] = lo + s_off[tid];
    if (b == NB - 1 && tid == 0) row_ptr[NN] = hi;
    if (inlds) {
        for (int i = tid; i < size; i += 512) {
            int2 e = s_e[i];
            int dl = (e.x >> 17) & 63;
            int p = atomicAdd(&s_cnt[dl], 1);
            csr[lo + p] = make_int2(e.x & 0x1FFFF, e.y);
        }
    } else {
        for (int i = tid; i < size; i += 512) {
            int2 e = tmp[lo + i];
            int dl = (e.x >> 17) & 63;
            int p = atomicAdd(&s_cnt[dl], 1);
            csr[lo + p] = make_int2(e.x & 0x1FFFF, e.y);
        }
    }
}

// ---- P5/P6: fused gather + MFMA for one 64-node bucket (8 waves) ----
template <bool RELU>
__device__ __forceinline__ void d_gather(const _Float16* __restrict__ feat, const int* __restrict__ row_ptr,
                                         const int2* __restrict__ csr, const _Float16* __restrict__ wt,
                                         const float* __restrict__ bias, _Float16* __restrict__ out,
                                         int bk, int tid, void* smem) {
    _Float16 (*atile)[LK] = (_Float16(*)[LK])smem;
    const int nb = bk << BSH;
    const int wave = tid >> 6;
    const int lane = tid & 63;
    const int q = lane >> 4;
    const int l16 = lane & 15;
    const int c8 = l16 << 3;

    // phase 1: gather 8 nodes per wave, 3-deep pipeline
    for (int nn = 0; nn < 8; nn++) {
        int local_n = wave * 8 + nn;
        int node = nb + local_n;
        if (node >= NN) break;                     // wave-uniform
        int r0 = row_ptr[node], r1 = row_ptr[node + 1];
        float acc[8] = {0.f, 0.f, 0.f, 0.f, 0.f, 0.f, 0.f, 0.f};
        int r = r0 + q;
        if (r < r1) {
            int2 e = csr[r];
            f16x8 v = *(const f16x8*)&feat[(size_t)e.x * CH + c8];
            int2 e2; f16x8 v2;
            bool h2 = (r + 4) < r1;
            if (h2) { e2 = csr[r + 4]; v2 = *(const f16x8*)&feat[(size_t)e2.x * CH + c8]; }
            for (int r3 = r + 8; r3 < r1; r3 += 4) {
                int2 e3 = csr[r3];
                f16x8 v3 = *(const f16x8*)&feat[(size_t)e3.x * CH + c8];
                float w = __int_as_float(e.y);
#pragma unroll
                for (int j = 0; j < 8; j++) acc[j] += w * (float)v[j];
                e = e2; v = v2;
                e2 = e3; v2 = v3;
            }
            float w = __int_as_float(e.y);
#pragma unroll
            for (int j = 0; j < 8; j++) acc[j] += w * (float)v[j];
            if (h2) {
                float w2 = __int_as_float(e2.y);
#pragma unroll
                for (int j = 0; j < 8; j++) acc[j] += w2 * (float)v2[j];
            }
        }
#pragma unroll
        for (int j = 0; j < 8; j++) {
            acc[j] += __shfl_xor(acc[j], 16, 64);
            acc[j] += __shfl_xor(acc[j], 32, 64);
        }
        if (q == 0) {
            float inv = 1.0f / fmaxf((float)(r1 - r0), 1.0f);
            f16x8 o;
#pragma unroll
            for (int j = 0; j < 8; j++) o[j] = (_Float16)(acc[j] * inv);
            *(f16x8*)&atile[local_n][c8] = o;
        }
    }

    // phase 2: stage self rows (coalesced)
    for (int i = tid; i < 64 * 16; i += 512) {
        int rrow = i >> 4;
        int cc8 = (i & 15) << 3;
        int gn = nb + rrow;
        f16x8 v = {};
        if (gn < NN) v = *(const f16x8*)&feat[(size_t)gn * CH + cc8];
        *(f16x8*)&atile[rrow][128 + cc8] = v;
    }
    __syncthreads();

    // phase 3: MFMA; wave w -> output cols w*16..w*16+15
    f32x4 ac[4];
#pragma unroll
    for (int m = 0; m < 4; m++) ac[m] = (f32x4){0.f, 0.f, 0.f, 0.f};

    const int ncol = wave * 16 + l16;
    const int kq = q * 8;
#pragma unroll
    for (int ks = 0; ks < 8; ks++) {
        int kbase = ks * 32 + kq;
        f16x8 bf = *(const f16x8*)&wt[(size_t)ncol * 256 + kbase];
#pragma unroll
        for (int m = 0; m < 4; m++) {
            f16x8 af = *(const f16x8*)&atile[m * 16 + l16][kbase];
            ac[m] = __builtin_amdgcn_mfma_f32_16x16x32_f16(af, bf, ac[m], 0, 0, 0);
        }
    }

    float bv = bias[ncol];
#pragma unroll
    for (int m = 0; m < 4; m++) {
#pragma unroll
        for (int r = 0; r < 4; r++) {
            int node = nb + m * 16 + q * 4 + r;
            if (node >= NN) continue;
            float v = ac[m][r] + bv;
            if (RELU) v = fmaxf(v, 0.f);
            out[(size_t)node * CH + ncol] = (_Float16)v;
        }
    }
}

// ---- P7: decode (half-wave per pair, 16B loads + shfl exchange) ----
__device__ __forceinline__ void d_decode(const _Float16* __restrict__ z,
                                         const int* __restrict__ ps, const int* __restrict__ pd,
                                         float* __restrict__ out, int gid, int gstride) {
    int lane32 = gid & 31;
    int l16 = lane32 & 15;
    int half = lane32 >> 4;
    for (int p = gid >> 5; p < NP; p += (gstride >> 5)) {
        int row = half ? pd[p] : ps[p];
        int4 a = *(const int4*)&z[(size_t)row * CH + l16 * 8];
        int4 b;
        b.x = __shfl_xor(a.x, 16, 64);
        b.y = __shfl_xor(a.y, 16, 64);
        b.z = __shfl_xor(a.z, 16, 64);
        b.w = __shfl_xor(a.w, 16, 64);
        union U { int4 i; f16x8 h; };
        U ua, ub; ua.i = a; ub.i = b;
        float v = 0.f;
#pragma unroll
        for (int j = 0; j < 8; j++) v += (float)ua.h[j] * (float)ub.h[j];
#pragma unroll
        for (int off = 8; off > 0; off >>= 1) v += __shfl_xor(v, off, 64);
        if (lane32 == 0) out[p] = v * 0.08838834764831845f;  // 1/sqrt(128)
    }
}

// ==== monolithic cooperative kernel: all phases + grid syncs ====
__global__ __launch_bounds__(512, 8)
void mono_kernel(Params P, int GB) {
    __shared__ alignas(16) unsigned char smem[SMEM_BYTES];
    cg::grid_group grid = cg::this_grid();
    const int bid = blockIdx.x, tid = threadIdx.x;
    const int gid = bid * 512 + tid, gstride = GB * 512;

    // P1: cast + weights + sync-reset + hist
    d_cast(P.x, P.xh, gid, gstride);
    d_weights(P.w1r, P.w1o, P.w2r, P.w2o, P.w1t, P.w2t, gid);
    if (gid == 0) *P.syncc = 0;
    d_hist(P.dst, P.hist, bid, GB, tid, smem);
    grid.sync();

    // P2: colscan + base (last-block chain inside)
    d_colscan(P.hist, P.totals, P.base, P.syncc, bid, GB, tid, smem);
    grid.sync();

    // P3: scatter
    d_scatter(P.src, P.dst, P.ew, P.hist, P.base, P.tmp, bid, GB, tid, smem);
    grid.sync();

    // P4: finalize
    for (int b = bid; b < NB; b += GB) {
        __syncthreads();
        d_finalize(P.tmp, P.base, P.row_ptr, P.csr, b, tid, smem);
    }
    grid.sync();

    // P5: gather layer 1 (relu)
    for (int b = bid; b < NB; b += GB) {
        __syncthreads();
        d_gather<true>(P.xh, P.row_ptr, P.csr, P.w1t, P.b1, P.hh, b, tid, smem);
    }
    grid.sync();

    // P6: gather layer 2
    for (int b = bid; b < NB; b += GB) {
        __syncthreads();
        d_gather<false>(P.hh, P.row_ptr, P.csr, P.w2t, P.b2, P.zh, b, tid, smem);
    }
    grid.sync();

    // P7: decode
    d_decode(P.zh, P.ps, P.pd, P.out, gid, gstride);
}

// ==== fallback wrappers (same phase code, separate launches) ====
__global__ __launch_bounds__(512) void k_p1(Params P, int GB) {
    __shared__ alignas(16) unsigned char smem[SMEM_BYTES];
    const int bid = blockIdx.x, tid = threadIdx.x;
    const int gid = bid * 512 + tid, gstride = GB * 512;
    d_cast(P.x, P.xh, gid, gstride);
    d_weights(P.w1r, P.w1o, P.w2r, P.w2o, P.w1t, P.w2t, gid);
    if (gid == 0) *P.syncc = 0;
    d_hist(P.dst, P.hist, bid, GB, tid, smem);
}
__global__ __launch_bounds__(512) void k_p2(Params P, int GB) {
    __shared__ alignas(16) unsigned char smem[SMEM_BYTES];
    d_colscan(P.hist, P.totals, P.base, P.syncc, blockIdx.x, GB, threadIdx.x, smem);
}
__global__ __launch_bounds__(512) void k_p3(Params P, int GB) {
    __shared__ alignas(16) unsigned char smem[SMEM_BYTES];
    d_scatter(P.src, P.dst, P.ew, P.hist, P.base, P.tmp, blockIdx.x, GB, threadIdx.x, smem);
}
__global__ __launch_bounds__(512) void k_p4(Params P, int GB) {
    __shared__ alignas(16) unsigned char smem[SMEM_BYTES];
    for (int b = blockIdx.x; b < NB; b += GB) {
        __syncthreads();
        d_finalize(P.tmp, P.base, P.row_ptr, P.csr, b, threadIdx.x, smem);
    }
}
__global__ __launch_bounds__(512) void k_p5(Params P, int GB) {
    __shared__ alignas(16) unsigned char smem[SMEM_BYTES];
    for (int b = blockIdx.x; b < NB; b += GB) {
        __syncthreads();
        d_gather<true>(P.xh, P.row_ptr, P.csr, P.w1t, P.b1, P.hh, b, threadIdx.x, smem);
    }
}
__global__ __launch_bounds__(512) void k_p6(Params P, int GB) {
    __shared__ alignas(16) unsigned char smem[SMEM_BYTES];
    for (int b = blockIdx.x; b < NB; b += GB) {
        __syncthreads();
        d_gather<false>(P.hh, P.row_ptr, P.csr, P.w2t, P.b2, P.zh, b, threadIdx.x, smem);
    }
}
__global__ __launch_bounds__(512) void k_p7(Params P, int GB) {
    const int gid = blockIdx.x * 512 + threadIdx.x;
    d_decode(P.zh, P.ps, P.pd, P.out, gid, GB * 512);
}

extern "C" void kernel_launch(void* const* d_in, const int* in_sizes, int n_in,
                              void* d_out, int out_size, void* d_ws, size_t ws_size,
                              hipStream_t stream) {
    const float* x       = (const float*)d_in[0];
    const int*   ei      = (const int*)d_in[1];   // [2, E]: src then dst
    const float* ew      = (const float*)d_in[2];
    const int*   eli     = (const int*)d_in[3];   // [2, P]
    const float* w1_rel  = (const float*)d_in[4];
    const float* b1      = (const float*)d_in[5];
    const float* w1_root = (const float*)d_in[6];
    const float* w2_rel  = (const float*)d_in[7];
    const float* b2      = (const float*)d_in[8];
    const float* w2_root = (const float*)d_in[9];

    const size_t hrow = (size_t)NN * CH * sizeof(_Float16);   // 25.6 MB

    char* ws = (char*)d_ws;
    size_t off = 0;
    auto alloc = [&](size_t bytes) { char* p = ws + off; off = (off + bytes + 15) & ~(size_t)15; return p; };
    Params P;
    P.xh      = (_Float16*)alloc(hrow);
    P.hh      = (_Float16*)alloc(hrow);
    P.zh      = (_Float16*)alloc(hrow);
    P.hist    = (int*)alloc((size_t)MAXGB * NB * 4);   // 6.4 MB worst case
    P.totals  = (int*)alloc((size_t)NB * 4);
    P.base    = (int*)alloc((size_t)(NB + 1) * 4);
    P.row_ptr = (int*)alloc((size_t)(NN + 1) * 4);
    P.syncc   = (int*)alloc(16);
    P.tmp     = (int2*)alloc((size_t)NE * 8);          // 12.8 MB
    P.csr     = (int2*)alloc((size_t)NE * 8);          // 12.8 MB
    P.w1t     = (_Float16*)alloc((size_t)128 * 256 * 2);
    P.w2t     = (_Float16*)alloc((size_t)128 * 256 * 2);

    P.x = x; P.src = ei; P.dst = ei + NE; P.ew = ew;
    P.ps = eli; P.pd = eli + NP;
    P.w1r = w1_rel; P.b1 = b1; P.w1o = w1_root;
    P.w2r = w2_rel; P.b2 = b2; P.w2o = w2_root;
    P.out = (float*)d_out;

    // grid = co-resident capacity (cooperative requirement), multiple of 8
    int maxb = 0;
    hipError_t qe = hipOccupancyMaxActiveBlocksPerMultiprocessor(&maxb, (const void*)mono_kernel, 512, 0);
    int GB = (qe == hipSuccess && maxb > 0) ? maxb * 256 : MAXGB;
    if (GB > MAXGB) GB = MAXGB;
    GB &= ~7;

    bool coop_ok = (GB >= 64);
    if (coop_ok) {
        void* args[] = { (void*)&P, (void*)&GB };
        hipError_t e = hipLaunchCooperativeKernel((const void*)mono_kernel, dim3(GB), dim3(512),
                                                  args, 0, stream);
        if (e != hipSuccess) { (void)hipGetLastError(); coop_ok = false; }
    }
    if (!coop_ok) {
        int GBF = MAXGB;
        k_p1<<<GBF, 512, 0, stream>>>(P, GBF);
        k_p2<<<CSB, 512, 0, stream>>>(P, GBF);
        k_p3<<<GBF, 512, 0, stream>>>(P, GBF);
        k_p4<<<GBF, 512, 0, stream>>>(P, GBF);
        k_p5<<<GBF, 512, 0, stream>>>(P, GBF);
        k_p6<<<GBF, 512, 0, stream>>>(P, GBF);
        k_p7<<<GBF, 512, 0, stream>>>(P, GBF);
    }
}

// Round 5
// 367.613 us; speedup vs baseline: 2.2701x; 2.2701x over previous
//
#include <hip/hip_runtime.h>

#define NN 100000
#define NE 1600000
#define NP 200000
#define CH 128
#define LK 264    // padded LDS row stride (fp16 elems)

#define BSH 6                    // 64 nodes per bucket
#define NB  1563                 // ceil(NN / 64)
#define G1  256                  // hist/scatter grid
#define EPB (NE / G1)            // 6250 edges per block
#define CAP3 4096                // finalize LDS edge capacity (mean bucket = 1024)
#define NCAST 6250               // cast blocks: NN*CH/8 / 256
#define CSG 25                   // colscan blocks: ceil(NB/64)

typedef _Float16 f16x8 __attribute__((ext_vector_type(8)));
typedef float f32x4 __attribute__((ext_vector_type(4)));

// ---- fused prep: [0,NCAST) cast x->fp16 | [NCAST,NCAST+G1) bucket hist | rest: weight prep ----
__global__ __launch_bounds__(256)
void fused_prep_kernel(const float* __restrict__ x, _Float16* __restrict__ xh,
                       const int* __restrict__ dst, int* __restrict__ hist,
                       const float* __restrict__ w1r, const float* __restrict__ w1o,
                       const float* __restrict__ w2r, const float* __restrict__ w2o,
                       _Float16* __restrict__ w1t, _Float16* __restrict__ w2t,
                       int* __restrict__ sync) {
    __shared__ int s_h[NB];
    const int bb = blockIdx.x, tid = threadIdx.x;
    if (bb < NCAST) {
        int i = bb * 256 + tid;   // i < 1.6M exactly
        const float4* p = (const float4*)x + (size_t)i * 2;
        float4 a = p[0], b = p[1];
        f16x8 o = { (_Float16)a.x, (_Float16)a.y, (_Float16)a.z, (_Float16)a.w,
                    (_Float16)b.x, (_Float16)b.y, (_Float16)b.z, (_Float16)b.w };
        *((f16x8*)xh + i) = o;
    } else if (bb < NCAST + G1) {
        int g = bb - NCAST;
        for (int i = tid; i < NB; i += 256) s_h[i] = 0;
        __syncthreads();
        int start = g * EPB, end = start + EPB;
        for (int e = start + tid; e < end; e += 256)
            atomicAdd(&s_h[dst[e] >> BSH], 1);
        __syncthreads();
        int* row = hist + (size_t)g * NB;
        for (int i = tid; i < NB; i += 256) row[i] = s_h[i];
    } else {
        int idx = (bb - NCAST - G1) * 256 + tid;   // < 65536
        if (idx == 0) *sync = 0;                   // reset colscan last-block counter
        int which = idx >> 15;
        int li = idx & 32767;
        int n = li >> 8, k = li & 255;
        const float* wr = which ? w2r : w1r;
        const float* wo = which ? w2o : w1o;
        _Float16* wt = which ? w2t : w1t;
        float v = (k < 128) ? wr[k * 128 + n] : wo[(k - 128) * 128 + n];
        wt[li] = (_Float16)v;
    }
}

// ---- column exclusive scan over g (coalesced, block per 64 buckets) + fused base-scan ----
__global__ __launch_bounds__(256)
void colscan_kernel(int* __restrict__ hist, int* __restrict__ totals,
                    int* __restrict__ base, int* __restrict__ sync) {
    __shared__ int qs[4][64];
    __shared__ int s_sync;
    __shared__ int ws[4];
    const int tid = threadIdx.x;
    const int q = tid >> 6, lb = tid & 63;
    const int b = blockIdx.x * 64 + lb;
    const bool valid = (b < NB);

    int s = 0;
    if (valid) {
        for (int g = q * 64; g < q * 64 + 64; ++g)
            s += hist[(size_t)g * NB + b];
    }
    qs[q][lb] = s;
    __syncthreads();

    if (tid < 64) {
        int a0 = qs[0][tid], a1 = qs[1][tid], a2 = qs[2][tid], a3 = qs[3][tid];
        qs[0][tid] = 0;
        qs[1][tid] = a0;
        qs[2][tid] = a0 + a1;
        qs[3][tid] = a0 + a1 + a2;
        int bt = blockIdx.x * 64 + tid;
        if (bt < NB) totals[bt] = a0 + a1 + a2 + a3;
    }
    __syncthreads();

    int run = qs[q][lb];
    if (valid) {
        for (int g = q * 64; g < q * 64 + 64; ++g) {
            size_t idx = (size_t)g * NB + b;
            int v = hist[idx];
            hist[idx] = run;
            run += v;
        }
    }

    // last-block: exclusive scan totals -> base
    __syncthreads();
    if (tid == 0) {
        __threadfence();
        s_sync = atomicAdd(sync, 1);
    }
    __syncthreads();
    if (s_sync != CSG - 1) return;
    __threadfence();

    const int c0 = tid * 7;
    int incl7[7];
    int cs = 0;
#pragma unroll
    for (int k = 0; k < 7; k++) {
        int i = c0 + k;
        int t = (i < NB) ? totals[i] : 0;
        cs += t;
        incl7[k] = cs;
    }
    int lane = tid & 63, w = tid >> 6;
    int incl = cs;
#pragma unroll
    for (int off = 1; off < 64; off <<= 1) {
        int n = __shfl_up(incl, off, 64);
        if (lane >= off) incl += n;
    }
    if (lane == 63) ws[w] = incl;
    __syncthreads();
    int woff = 0;
    for (int j = 0; j < w; j++) woff += ws[j];
    int chunk_excl = woff + incl - cs;
    if (tid == 0) base[0] = 0;
#pragma unroll
    for (int k = 0; k < 7; k++) {
        int i = c0 + k;
        if (i < NB) base[i + 1] = chunk_excl + incl7[k];
    }
}

// ---- scatter edges into bucket regions; x = src | dst_local<<17, y = fp32 weight ----
__global__ __launch_bounds__(512)
void bucket_scatter_kernel(const int* __restrict__ src, const int* __restrict__ dst,
                           const float* __restrict__ ew, const int* __restrict__ hist,
                           const int* __restrict__ base, int2* __restrict__ tmp) {
    __shared__ int s_cur[NB];
    const int* row = hist + (size_t)blockIdx.x * NB;
    for (int i = threadIdx.x; i < NB; i += 512) s_cur[i] = base[i] + row[i];
    __syncthreads();
    int start = blockIdx.x * EPB, end = start + EPB;
    for (int e = start + threadIdx.x; e < end; e += 512) {
        int d = dst[e];
        int b = d >> BSH;
        int pos = atomicAdd(&s_cur[b], 1);
        tmp[pos] = make_int2(src[e] | ((d & 63) << 17), __float_as_int(ew[e]));
    }
}

// ---- FUSED finalize + gather-layer-1: one block per bucket ----
// Stage A (finalize): sort bucket edges into node-grouped csr, write row_ptr, keep
//   per-node offsets in LDS.  Stage B (gather+MFMA): same block immediately consumes
//   its own csr region (L2-hot, same XCD) with r0/r1 from LDS instead of row_ptr loads.
__global__ __launch_bounds__(512)
void finalize_gather1_kernel(const int2* __restrict__ tmp, const int* __restrict__ base,
                             int* __restrict__ row_ptr, int2* __restrict__ csr,
                             const _Float16* __restrict__ feat, const _Float16* __restrict__ wt,
                             const float* __restrict__ bias, _Float16* __restrict__ out, int N) {
    __shared__ union alignas(16) {
        int2 s_e[CAP3];                  // 32768 B  (stage A)
        _Float16 atile[64][LK];          // 33792 B  (stage B)
    } u;
    __shared__ int s_cnt[64], s_off[65];

    const int b = blockIdx.x;
    const int tid = threadIdx.x;
    const int lo = base[b], hi = base[b + 1];
    const int size = hi - lo;
    const int nbase = b << BSH;
    const int ncnt = min(64, N - nbase);

    // ---- stage A: finalize ----
    if (tid < 64) s_cnt[tid] = 0;
    bool inlds = (size <= CAP3);
    __syncthreads();
    if (inlds) {
        for (int i = tid; i < size; i += 512) {
            int2 e = tmp[lo + i];
            u.s_e[i] = e;
            atomicAdd(&s_cnt[(e.x >> 17) & 63], 1);
        }
    } else {
        for (int i = tid; i < size; i += 512) {
            int2 e = tmp[lo + i];
            atomicAdd(&s_cnt[(e.x >> 17) & 63], 1);
        }
    }
    __syncthreads();
    if (tid < 64) {   // wave 0: shuffle exclusive scan
        int v = s_cnt[tid];
        int incl = v;
#pragma unroll
        for (int off = 1; off < 64; off <<= 1) {
            int n = __shfl_up(incl, off, 64);
            if (tid >= off) incl += n;
        }
        int excl = incl - v;
        s_off[tid] = excl;
        s_cnt[tid] = excl;
        if (tid == 63) s_off[64] = incl;   // total
    }
    __syncthreads();
    if (tid < ncnt) row_ptr[nbase + tid] = lo + s_off[tid];
    if (b == NB - 1 && tid == 0) row_ptr[N] = hi;
    if (inlds) {
        for (int i = tid; i < size; i += 512) {
            int2 e = u.s_e[i];
            int dl = (e.x >> 17) & 63;
            int p = atomicAdd(&s_cnt[dl], 1);
            csr[lo + p] = make_int2(e.x & 0x1FFFF, e.y);
        }
    } else {
        for (int i = tid; i < size; i += 512) {
            int2 e = tmp[lo + i];
            int dl = (e.x >> 17) & 63;
            int p = atomicAdd(&s_cnt[dl], 1);
            csr[lo + p] = make_int2(e.x & 0x1FFFF, e.y);
        }
    }
    __syncthreads();   // csr stores drained (vmcnt 0 before barrier) + s_off stable

    // ---- stage B: gather + MFMA (r3-proven code; r0/r1 from LDS) ----
    const int wave = tid >> 6;
    const int lane = tid & 63;
    const int q = lane >> 4;
    const int l16 = lane & 15;
    const int c8 = l16 << 3;

    for (int nn = 0; nn < 8; nn++) {
        int local_n = wave * 8 + nn;
        int node = nbase + local_n;
        if (node >= N) break;                      // wave-uniform
        int r0 = lo + s_off[local_n], r1 = lo + s_off[local_n + 1];
        float acc[8] = {0.f, 0.f, 0.f, 0.f, 0.f, 0.f, 0.f, 0.f};
        int r = r0 + q;
        if (r < r1) {
            int2 e = csr[r];
            f16x8 v = *(const f16x8*)&feat[(size_t)e.x * CH + c8];
            int2 e2; f16x8 v2;
            bool h2 = (r + 4) < r1;
            if (h2) { e2 = csr[r + 4]; v2 = *(const f16x8*)&feat[(size_t)e2.x * CH + c8]; }
            for (int r3 = r + 8; r3 < r1; r3 += 4) {
                int2 e3 = csr[r3];
                f16x8 v3 = *(const f16x8*)&feat[(size_t)e3.x * CH + c8];
                float w = __int_as_float(e.y);
#pragma unroll
                for (int j = 0; j < 8; j++) acc[j] += w * (float)v[j];
                e = e2; v = v2;
                e2 = e3; v2 = v3;
            }
            float w = __int_as_float(e.y);
#pragma unroll
            for (int j = 0; j < 8; j++) acc[j] += w * (float)v[j];
            if (h2) {
                float w2 = __int_as_float(e2.y);
#pragma unroll
                for (int j = 0; j < 8; j++) acc[j] += w2 * (float)v2[j];
            }
        }
#pragma unroll
        for (int j = 0; j < 8; j++) {
            acc[j] += __shfl_xor(acc[j], 16, 64);
            acc[j] += __shfl_xor(acc[j], 32, 64);
        }
        if (q == 0) {
            float inv = 1.0f / fmaxf((float)(r1 - r0), 1.0f);
            f16x8 o;
#pragma unroll
            for (int j = 0; j < 8; j++) o[j] = (_Float16)(acc[j] * inv);
            *(f16x8*)&u.atile[local_n][c8] = o;
        }
    }

    for (int i = tid; i < 64 * 16; i += 512) {
        int rrow = i >> 4;
        int cc8 = (i & 15) << 3;
        int gn = nbase + rrow;
        f16x8 v = {};
        if (gn < N) v = *(const f16x8*)&feat[(size_t)gn * CH + cc8];
        *(f16x8*)&u.atile[rrow][128 + cc8] = v;
    }
    __syncthreads();

    f32x4 ac[4];
#pragma unroll
    for (int m = 0; m < 4; m++) ac[m] = (f32x4){0.f, 0.f, 0.f, 0.f};

    const int ncol = wave * 16 + l16;
    const int kq = q * 8;
#pragma unroll
    for (int ks = 0; ks < 8; ks++) {
        int kbase = ks * 32 + kq;
        f16x8 bf = *(const f16x8*)&wt[(size_t)ncol * 256 + kbase];
#pragma unroll
        for (int m = 0; m < 4; m++) {
            f16x8 af = *(const f16x8*)&u.atile[m * 16 + l16][kbase];
            ac[m] = __builtin_amdgcn_mfma_f32_16x16x32_f16(af, bf, ac[m], 0, 0, 0);
        }
    }

    float bv = bias[ncol];
#pragma unroll
    for (int m = 0; m < 4; m++) {
#pragma unroll
        for (int r = 0; r < 4; r++) {
            int node = nbase + m * 16 + q * 4 + r;
            if (node >= N) continue;
            float v = ac[m][r] + bv;
            v = fmaxf(v, 0.f);                     // layer-1 ReLU
            out[(size_t)node * CH + ncol] = (_Float16)v;
        }
    }
}

// ---- gather + MFMA layer 2 (r3-proven standalone) ----
template <bool RELU>
__global__ __launch_bounds__(512)
void gatherlayer_kernel(const _Float16* __restrict__ feat, const int* __restrict__ row_ptr,
                        const int2* __restrict__ csr, const _Float16* __restrict__ wt,
                        const float* __restrict__ bias, _Float16* __restrict__ out, int N) {
    __shared__ _Float16 atile[64][LK];   // 33792 B -> 4 blocks/CU = 32 waves/CU

    const int tid = threadIdx.x;
    const int nb = blockIdx.x << BSH;
    const int wave = tid >> 6;
    const int lane = tid & 63;
    const int q = lane >> 4;
    const int l16 = lane & 15;
    const int c8 = l16 << 3;

    for (int nn = 0; nn < 8; nn++) {
        int local_n = wave * 8 + nn;
        int node = nb + local_n;
        if (node >= N) break;                      // wave-uniform
        int r0 = row_ptr[node], r1 = row_ptr[node + 1];
        float acc[8] = {0.f, 0.f, 0.f, 0.f, 0.f, 0.f, 0.f, 0.f};
        int r = r0 + q;
        if (r < r1) {
            int2 e = csr[r];
            f16x8 v = *(const f16x8*)&feat[(size_t)e.x * CH + c8];
            int2 e2; f16x8 v2;
            bool h2 = (r + 4) < r1;
            if (h2) { e2 = csr[r + 4]; v2 = *(const f16x8*)&feat[(size_t)e2.x * CH + c8]; }
            for (int r3 = r + 8; r3 < r1; r3 += 4) {
                int2 e3 = csr[r3];
                f16x8 v3 = *(const f16x8*)&feat[(size_t)e3.x * CH + c8];
                float w = __int_as_float(e.y);
#pragma unroll
                for (int j = 0; j < 8; j++) acc[j] += w * (float)v[j];
                e = e2; v = v2;
                e2 = e3; v2 = v3;
            }
            float w = __int_as_float(e.y);
#pragma unroll
            for (int j = 0; j < 8; j++) acc[j] += w * (float)v[j];
            if (h2) {
                float w2 = __int_as_float(e2.y);
#pragma unroll
                for (int j = 0; j < 8; j++) acc[j] += w2 * (float)v2[j];
            }
        }
#pragma unroll
        for (int j = 0; j < 8; j++) {
            acc[j] += __shfl_xor(acc[j], 16, 64);
            acc[j] += __shfl_xor(acc[j], 32, 64);
        }
        if (q == 0) {
            float inv = 1.0f / fmaxf((float)(r1 - r0), 1.0f);
            f16x8 o;
#pragma unroll
            for (int j = 0; j < 8; j++) o[j] = (_Float16)(acc[j] * inv);
            *(f16x8*)&atile[local_n][c8] = o;
        }
    }

    for (int i = tid; i < 64 * 16; i += 512) {
        int rrow = i >> 4;
        int cc8 = (i & 15) << 3;
        int gn = nb + rrow;
        f16x8 v = {};
        if (gn < N) v = *(const f16x8*)&feat[(size_t)gn * CH + cc8];
        *(f16x8*)&atile[rrow][128 + cc8] = v;
    }
    __syncthreads();

    f32x4 ac[4];
#pragma unroll
    for (int m = 0; m < 4; m++) ac[m] = (f32x4){0.f, 0.f, 0.f, 0.f};

    const int ncol = wave * 16 + l16;
    const int kq = q * 8;
#pragma unroll
    for (int ks = 0; ks < 8; ks++) {
        int kbase = ks * 32 + kq;
        f16x8 bf = *(const f16x8*)&wt[(size_t)ncol * 256 + kbase];
#pragma unroll
        for (int m = 0; m < 4; m++) {
            f16x8 af = *(const f16x8*)&atile[m * 16 + l16][kbase];
            ac[m] = __builtin_amdgcn_mfma_f32_16x16x32_f16(af, bf, ac[m], 0, 0, 0);
        }
    }

    float bv = bias[ncol];
#pragma unroll
    for (int m = 0; m < 4; m++) {
#pragma unroll
        for (int r = 0; r < 4; r++) {
            int node = nb + m * 16 + q * 4 + r;
            if (node >= N) continue;
            float v = ac[m][r] + bv;
            if (RELU) v = fmaxf(v, 0.f);
            out[(size_t)node * CH + ncol] = (_Float16)v;
        }
    }
}

// ---- decode: half-wave per pair; 16B loads (16 lanes per row) + shfl exchange ----
__global__ void decode_kernel(const _Float16* __restrict__ z,
                              const int* __restrict__ ps,
                              const int* __restrict__ pd,
                              float* __restrict__ out, int P) {
    long tid = (long)blockIdx.x * blockDim.x + threadIdx.x;
    int p = (int)(tid >> 5);
    int lane32 = (int)(tid & 31);
    if (p >= P) return;
    int l16 = lane32 & 15;
    int half = lane32 >> 4;                 // 0: s-row, 1: d-row
    int row = half ? pd[p] : ps[p];
    int4 a = *(const int4*)&z[(size_t)row * CH + l16 * 8];
    int4 b;
    b.x = __shfl_xor(a.x, 16, 64);
    b.y = __shfl_xor(a.y, 16, 64);
    b.z = __shfl_xor(a.z, 16, 64);
    b.w = __shfl_xor(a.w, 16, 64);
    union U { int4 i; f16x8 h; };
    U ua, ub; ua.i = a; ub.i = b;
    float v = 0.f;
#pragma unroll
    for (int j = 0; j < 8; j++) v += (float)ua.h[j] * (float)ub.h[j];
#pragma unroll
    for (int off = 8; off > 0; off >>= 1) v += __shfl_xor(v, off, 64);
    if (lane32 == 0) out[p] = v * 0.08838834764831845f;  // 1/sqrt(128)
}

extern "C" void kernel_launch(void* const* d_in, const int* in_sizes, int n_in,
                              void* d_out, int out_size, void* d_ws, size_t ws_size,
                              hipStream_t stream) {
    const float* x       = (const float*)d_in[0];
    const int*   ei      = (const int*)d_in[1];   // [2, E]: src then dst
    const float* ew      = (const float*)d_in[2];
    const int*   eli     = (const int*)d_in[3];   // [2, P]
    const float* w1_rel  = (const float*)d_in[4];
    const float* b1      = (const float*)d_in[5];
    const float* w1_root = (const float*)d_in[6];
    const float* w2_rel  = (const float*)d_in[7];
    const float* b2      = (const float*)d_in[8];
    const float* w2_root = (const float*)d_in[9];
    float* out = (float*)d_out;

    const int N = NN, E = NE, P = NP;
    const size_t hrow = (size_t)N * CH * sizeof(_Float16);   // 25.6 MB

    char* ws = (char*)d_ws;
    size_t off = 0;
    auto alloc = [&](size_t bytes) { char* p = ws + off; off = (off + bytes + 15) & ~(size_t)15; return p; };
    _Float16* xh  = (_Float16*)alloc(hrow);
    _Float16* hh  = (_Float16*)alloc(hrow);
    _Float16* zh  = (_Float16*)alloc(hrow);
    int* hist     = (int*)alloc((size_t)G1 * NB * 4);    // 1.6 MB
    int* totals   = (int*)alloc((size_t)NB * 4);
    int* base     = (int*)alloc((size_t)(NB + 1) * 4);
    int* row_ptr  = (int*)alloc((size_t)(N + 1) * 4);
    int* sync     = (int*)alloc(16);
    int2* tmp     = (int2*)alloc((size_t)E * 8);         // 12.8 MB
    int2* csr     = (int2*)alloc((size_t)E * 8);         // 12.8 MB
    _Float16* w1t = (_Float16*)alloc((size_t)128 * 256 * 2);
    _Float16* w2t = (_Float16*)alloc((size_t)128 * 256 * 2);

    const int* src = ei;
    const int* dst = ei + E;

    // --- fused prep: cast + hist + weight transpose (+ sync reset) ---
    fused_prep_kernel<<<NCAST + G1 + 256, 256, 0, stream>>>(
        x, xh, dst, hist, w1_rel, w1_root, w2_rel, w2_root, w1t, w2t, sync);

    // --- CSR build ---
    colscan_kernel<<<CSG, 256, 0, stream>>>(hist, totals, base, sync);
    bucket_scatter_kernel<<<G1, 512, 0, stream>>>(src, dst, ew, hist, base, tmp);

    // --- fused finalize + gather layer 1 ---
    finalize_gather1_kernel<<<NB, 512, 0, stream>>>(tmp, base, row_ptr, csr,
                                                    xh, w1t, b1, hh, N);

    // --- gather layer 2 ---
    gatherlayer_kernel<false><<<NB, 512, 0, stream>>>(hh, row_ptr, csr, w2t, b2, zh, N);

    // --- decode ---
    {
        long threads = (long)P * 32;
        decode_kernel<<<(int)((threads + 255) / 256), 256, 0, stream>>>(zh, eli, eli + P, out, P);
    }
}